// Round 4
// baseline (873.056 us; speedup 1.0000x reference)
//
#include <hip/hip_runtime.h>

typedef short bf16x4 __attribute__((ext_vector_type(4)));
typedef short bf16x8 __attribute__((ext_vector_type(8)));
typedef float f32x4  __attribute__((ext_vector_type(4)));

#define MFMA16(a, b, c) __builtin_amdgcn_mfma_f32_16x16x16bf16_1k(a, b, c, 0, 0, 0)
#define MFMA32(a, b, c) __builtin_amdgcn_mfma_f32_16x16x32_bf16(a, b, c, 0, 0, 0)

constexpr int D = 256;
constexpr int S = 4096;
constexpr int BATCH = 4;
constexpr int NROWS = BATCH * S;   // 16384
constexpr float SCALE = 0.0625f;   // 1/sqrt(256)

// ---------------- async global->LDS (gfx950) ----------------
__device__ __forceinline__ void gll16(const void* g, void* l) {
  __builtin_amdgcn_global_load_lds(
      (const __attribute__((address_space(1))) unsigned int*)g,
      (__attribute__((address_space(3))) unsigned int*)l, 16, 0, 0);
}
__device__ __forceinline__ void gll4(const void* g, void* l) {
  __builtin_amdgcn_global_load_lds(
      (const __attribute__((address_space(1))) unsigned int*)g,
      (__attribute__((address_space(3))) unsigned int*)l, 4, 0, 0);
}

// ---------------- bf16 split helpers (RNE) ----------------
__device__ __forceinline__ unsigned short f2bf(float v) {
  union { float f; unsigned u; } x; x.f = v;
  unsigned r = x.u + 0x7fffu + ((x.u >> 16) & 1u);
  return (unsigned short)(r >> 16);
}
__device__ __forceinline__ float bf2f(unsigned short h) {
  union { unsigned u; float f; } x; x.u = ((unsigned)h) << 16; return x.f;
}
__device__ __forceinline__ void split2(float v, unsigned short& hi, unsigned short& lo) {
  hi = f2bf(v);
  lo = f2bf(v - bf2f(hi));
}

union U8 { unsigned short s[8]; uint4 v; };

// ---------------------------------------------------------------------------
// QKV projection (unchanged from round 3, known-good)
// ---------------------------------------------------------------------------
__global__ __launch_bounds__(256)
void qkv_split_kernel(const float* __restrict__ in,
                      const float* __restrict__ wq, const float* __restrict__ bq,
                      const float* __restrict__ wk, const float* __restrict__ bk,
                      const float* __restrict__ wv, const float* __restrict__ bv,
                      unsigned short* __restrict__ Qh, unsigned short* __restrict__ Ql,
                      unsigned short* __restrict__ Kh, unsigned short* __restrict__ Kl,
                      unsigned short* __restrict__ Vth, unsigned short* __restrict__ Vtl)
{
  const int m = blockIdx.y;
  const float* W    = (m == 0) ? wq : (m == 1) ? wk : wv;
  const float* bias = (m == 0) ? bq : (m == 1) ? bk : bv;
  const int rb = blockIdx.x * 64;
  const int col_off = m * D;

  __shared__ float xs[64][256];
  const int tid = threadIdx.x;
#pragma unroll
  for (int it = 0; it < 16; ++it) {
    int f4 = it * 256 + tid;
    int row = f4 >> 6;
    int c4 = (f4 & 63) << 2;
    *(float4*)&xs[row][c4] =
        *(const float4*)(in + (size_t)(rb + row) * (3 * D) + col_off + c4);
  }
  __syncthreads();

  const int c0 = (tid & 31) * 8;
  const int r0 = (tid >> 5) * 8;
  float acc[8][8];
#pragma unroll
  for (int rr = 0; rr < 8; ++rr)
#pragma unroll
    for (int cc = 0; cc < 8; ++cc) acc[rr][cc] = 0.0f;

  for (int i4 = 0; i4 < 64; ++i4) {
    float4 x4[8];
#pragma unroll
    for (int rr = 0; rr < 8; ++rr)
      x4[rr] = *(const float4*)&xs[r0 + rr][i4 * 4];
#pragma unroll
    for (int di = 0; di < 4; ++di) {
      const float* wrow = W + (size_t)(i4 * 4 + di) * 256 + c0;
      float4 w0 = *(const float4*)(wrow);
      float4 w1 = *(const float4*)(wrow + 4);
#pragma unroll
      for (int rr = 0; rr < 8; ++rr) {
        float xv = (di == 0) ? x4[rr].x
                 : (di == 1) ? x4[rr].y
                 : (di == 2) ? x4[rr].z : x4[rr].w;
        acc[rr][0] += xv * w0.x;  acc[rr][1] += xv * w0.y;
        acc[rr][2] += xv * w0.z;  acc[rr][3] += xv * w0.w;
        acc[rr][4] += xv * w1.x;  acc[rr][5] += xv * w1.y;
        acc[rr][6] += xv * w1.z;  acc[rr][7] += xv * w1.w;
      }
    }
  }

  float bv8[8];
#pragma unroll
  for (int cc = 0; cc < 8; ++cc) bv8[cc] = bias[c0 + cc];

  if (m < 2) {
    unsigned short* H = (m == 0) ? Qh : Kh;
    unsigned short* L = (m == 0) ? Ql : Kl;
    const float sc = (m == 0) ? SCALE : 1.0f;
#pragma unroll
    for (int rr = 0; rr < 8; ++rr) {
      U8 uh, ul;
#pragma unroll
      for (int cc = 0; cc < 8; ++cc) {
        float v = (acc[rr][cc] + bv8[cc]) * sc;
        split2(v, uh.s[cc], ul.s[cc]);
      }
      size_t a = (size_t)(rb + r0 + rr) * 256 + c0;
      *(uint4*)&H[a] = uh.v;
      *(uint4*)&L[a] = ul.v;
    }
  } else {
    const int b  = (rb + r0) >> 12;
    const int s0 = (rb + r0) & 4095;
#pragma unroll
    for (int cc = 0; cc < 8; ++cc) {
      U8 uh, ul;
#pragma unroll
      for (int rr = 0; rr < 8; ++rr) {
        float v = acc[rr][cc] + bv8[cc];
        split2(v, uh.s[rr], ul.s[rr]);
      }
      size_t a = ((size_t)(b * 256 + c0 + cc)) * 4096 + s0;
      *(uint4*)&Vth[a] = uh.v;
      *(uint4*)&Vtl[a] = ul.v;
    }
  }
}

// ---------------------------------------------------------------------------
// Output projection (unchanged)
// ---------------------------------------------------------------------------
__global__ __launch_bounds__(256)
void oproj_kernel(const float* __restrict__ wo, const float* __restrict__ bo,
                  float* out)
{
  const int rb = blockIdx.x * 64;
  __shared__ float xs[64][256];
  const int tid = threadIdx.x;
#pragma unroll
  for (int it = 0; it < 16; ++it) {
    int f4 = it * 256 + tid;
    int row = f4 >> 6;
    int c4 = (f4 & 63) << 2;
    *(float4*)&xs[row][c4] = *(const float4*)(out + (size_t)(rb + row) * 256 + c4);
  }
  __syncthreads();

  const int c0 = (tid & 31) * 8;
  const int r0 = (tid >> 5) * 8;
  float acc[8][8];
#pragma unroll
  for (int rr = 0; rr < 8; ++rr)
#pragma unroll
    for (int cc = 0; cc < 8; ++cc) acc[rr][cc] = 0.0f;

  for (int i4 = 0; i4 < 64; ++i4) {
    float4 x4[8];
#pragma unroll
    for (int rr = 0; rr < 8; ++rr)
      x4[rr] = *(const float4*)&xs[r0 + rr][i4 * 4];
#pragma unroll
    for (int di = 0; di < 4; ++di) {
      const float* wrow = wo + (size_t)(i4 * 4 + di) * 256 + c0;
      float4 w0 = *(const float4*)(wrow);
      float4 w1 = *(const float4*)(wrow + 4);
#pragma unroll
      for (int rr = 0; rr < 8; ++rr) {
        float xv = (di == 0) ? x4[rr].x
                 : (di == 1) ? x4[rr].y
                 : (di == 2) ? x4[rr].z : x4[rr].w;
        acc[rr][0] += xv * w0.x;  acc[rr][1] += xv * w0.y;
        acc[rr][2] += xv * w0.z;  acc[rr][3] += xv * w0.w;
        acc[rr][4] += xv * w1.x;  acc[rr][5] += xv * w1.y;
        acc[rr][6] += xv * w1.z;  acc[rr][7] += xv * w1.w;
      }
    }
  }

  float4 b0 = *(const float4*)(bo + c0);
  float4 b1 = *(const float4*)(bo + c0 + 4);
#pragma unroll
  for (int rr = 0; rr < 8; ++rr) {
    float4 v0, v1;
    v0.x = acc[rr][0] + b0.x; v0.y = acc[rr][1] + b0.y;
    v0.z = acc[rr][2] + b0.z; v0.w = acc[rr][3] + b0.w;
    v1.x = acc[rr][4] + b1.x; v1.y = acc[rr][5] + b1.y;
    v1.z = acc[rr][6] + b1.z; v1.w = acc[rr][7] + b1.w;
    float* op = out + (size_t)(rb + r0 + rr) * 256 + c0;
    *(float4*)op = v0;
    *(float4*)(op + 4) = v1;
  }
}

// ---------------------------------------------------------------------------
// MFMA flash attention v3. 256 blocks x 256 thr (4 waves, Tq=32/wave).
// combo = bx&7 -> (b = combo>>1, kz = combo&1), qb = bx>>3 in [0,32).
// LDS frag-major, double-buffered (2 x 32KB); staging via global_load_lds
// (lane-linear => conflict-free). Q-hi register-resident; Q-lo streamed
// from global (L2) with a 2-slot pipeline. kz0 partial -> Xp(=d_out).
// ---------------------------------------------------------------------------
__global__ __launch_bounds__(256, 2)
void attn3_kernel(const unsigned short* __restrict__ QhG, const unsigned short* __restrict__ QlG,
                  const unsigned short* __restrict__ KhG, const unsigned short* __restrict__ KlG,
                  const unsigned short* __restrict__ VthG, const unsigned short* __restrict__ VtlG,
                  float* __restrict__ Xp, float* __restrict__ Op,
                  float* __restrict__ Mp, float* __restrict__ Lp)
{
  // buf layout (bytes, per 32KB buffer):
  //   K: [(kc*2+hl)*1024 + lane*16], kc 0..7       -> [0, 16384)
  //   V: [16384 + (ct*2+hl)*512 + lane*8], ct 0..15 -> [16384, 32768)
  __shared__ __align__(16) unsigned char KVs[2][32768];

  const int tid  = threadIdx.x;
  const int lane = tid & 63;
  const int w    = tid >> 6;        // wave 0..3
  const int l15  = lane & 15;
  const int quad = lane >> 4;

  const int bx    = blockIdx.x;
  const int combo = bx & 7;         // XCD-pinned (b,kz)
  const int b     = combo >> 1;
  const int kz    = combo & 1;
  const int qb    = bx >> 3;        // 0..31
  const int qrow0 = qb * 128 + w * 32;          // within batch
  const int grow  = b * 4096 + qrow0;           // global row
  const int k0    = kz * 2048;

  // ---- resident Q-hi fragments (B-frag: n=q=l15, k=quad*8+j per kc)
  bf16x8 qh[2][8];
#pragma unroll
  for (int qs = 0; qs < 2; ++qs) {
    const size_t qoff = ((size_t)(grow + qs * 16 + l15)) * 256 + quad * 8;
#pragma unroll
    for (int kc = 0; kc < 8; ++kc)
      qh[qs][kc] = *(const bf16x8*)(QhG + qoff + kc * 32);
  }
  // Q-lo stream bases (constant across tiles)
  const unsigned short* qlb0 = QlG + ((size_t)(grow + l15)) * 256 + quad * 8;
  const unsigned short* qlb1 = QlG + ((size_t)(grow + 16 + l15)) * 256 + quad * 8;

  // ---- per-lane staging pointers
  // K: lane -> key=lane&15, d-chunk quad=lane>>4; wave w stages kc {2w,2w+1}
  const unsigned short* kgh = KhG + ((size_t)(b * 4096 + k0 + (lane & 15))) * 256
                              + (2 * w) * 32 + (lane >> 4) * 8;
  const unsigned short* kgl = KlG + ((size_t)(b * 4096 + k0 + (lane & 15))) * 256
                              + (2 * w) * 32 + (lane >> 4) * 8;
  // V: wave w stages cts {4w..4w+3}; lane -> dim=(ct*16+((lane>>1)&15)),
  //    key=( (lane>>5)*4 + (lane&1)*2 ), i adds +8 keys (ptr+8)
  const unsigned short* vgh = VthG + ((size_t)(b * 256 + (w * 4) * 16 + ((lane >> 1) & 15))) * 4096
                              + k0 + (lane >> 5) * 4 + (lane & 1) * 2;
  const unsigned short* vgl = VtlG + ((size_t)(b * 256 + (w * 4) * 16 + ((lane >> 1) & 15))) * 4096
                              + k0 + (lane >> 5) * 4 + (lane & 1) * 2;

  // ---- stage one tile into buffer `buf`
  auto stage = [&](int buf) {
    unsigned char* kb = &KVs[buf][0];
    gll16(kgh,      kb + (4 * w + 0) * 1024);
    gll16(kgl,      kb + (4 * w + 1) * 1024);
    gll16(kgh + 32, kb + (4 * w + 2) * 1024);
    gll16(kgl + 32, kb + (4 * w + 3) * 1024);
    unsigned char* vb = kb + 16384 + w * 4096;
    const unsigned short* ph = vgh;
    const unsigned short* pl = vgl;
#pragma unroll
    for (int cc = 0; cc < 4; ++cc) {
      gll4(ph,     vb + cc * 1024);
      gll4(ph + 8, vb + cc * 1024 + 256);
      gll4(pl,     vb + cc * 1024 + 512);
      gll4(pl + 8, vb + cc * 1024 + 768);
      ph += 65536;  pl += 65536;
    }
  };

  f32x4 o0[16], o1[16];
#pragma unroll
  for (int ct = 0; ct < 16; ++ct) {
    o0[ct] = (f32x4){0.f, 0.f, 0.f, 0.f};
    o1[ct] = (f32x4){0.f, 0.f, 0.f, 0.f};
  }
  float m0 = -3.0e38f, m1 = -3.0e38f, l0 = 0.f, l1 = 0.f;

  stage(0);
  kgh += 4096; kgl += 4096; vgh += 16; vgl += 16;   // next tile (keys += 16)

  const int laneK = lane * 16;   // K frag byte offset
  const int laneV = lane * 8;    // V frag byte offset

  for (int kt = 0; kt < 128; ++kt) {
    // pre-load Ql slots kc=0,1 (complete by the barrier's vmcnt drain)
    bf16x8 qla[2][2];
    qla[0][0] = *(const bf16x8*)(qlb0);
    qla[0][1] = *(const bf16x8*)(qlb1);
    qla[1][0] = *(const bf16x8*)(qlb0 + 32);
    qla[1][1] = *(const bf16x8*)(qlb1 + 32);

    __syncthreads();               // staging for tile kt complete
    const unsigned char* Kb = &KVs[kt & 1][0];

    // ---- QK: S^T (3-pass split), Tk=16, both q-subtiles
    f32x4 st0 = (f32x4){0.f, 0.f, 0.f, 0.f};
    f32x4 st1 = (f32x4){0.f, 0.f, 0.f, 0.f};
#pragma unroll
    for (int kc = 0; kc < 8; ++kc) {
      bf16x8 kh = *(const bf16x8*)(Kb + (kc * 2 + 0) * 1024 + laneK);
      bf16x8 kl = *(const bf16x8*)(Kb + (kc * 2 + 1) * 1024 + laneK);
      bf16x8 q0 = qla[kc & 1][0];
      bf16x8 q1 = qla[kc & 1][1];
      if (kc < 6) {
        qla[kc & 1][0] = *(const bf16x8*)(qlb0 + (kc + 2) * 32);
        qla[kc & 1][1] = *(const bf16x8*)(qlb1 + (kc + 2) * 32);
      }
      st0 = MFMA32(kh, qh[0][kc], st0);
      st0 = MFMA32(kl, qh[0][kc], st0);
      st0 = MFMA32(kh, q0, st0);
      st1 = MFMA32(kh, qh[1][kc], st1);
      st1 = MFMA32(kl, qh[1][kc], st1);
      st1 = MFMA32(kh, q1, st1);
    }

    // ---- stage next tile (after all Ql loads, before long PV phase)
    if (kt < 127) {
      stage((kt + 1) & 1);
      kgh += 4096; kgl += 4096; vgh += 16; vgl += 16;
    }

    // ---- online softmax per q-subtile (lane: q=l15, keys quad*4+r)
    float mn0, mn1, al0, al1;
    bf16x4 pah0, pal0, pah1, pal1;
    {
      float t = fmaxf(fmaxf(st0[0], st0[1]), fmaxf(st0[2], st0[3]));
      t = fmaxf(t, __shfl_xor(t, 16));
      t = fmaxf(t, __shfl_xor(t, 32));
      mn0 = fmaxf(m0, t);
      al0 = __expf(m0 - mn0);
      float p0 = __expf(st0[0] - mn0), p1 = __expf(st0[1] - mn0);
      float p2 = __expf(st0[2] - mn0), p3 = __expf(st0[3] - mn0);
      float ps = (p0 + p1) + (p2 + p3);
      ps += __shfl_xor(ps, 16);
      ps += __shfl_xor(ps, 32);
      l0 = l0 * al0 + ps;
      unsigned short h0, h1, h2, h3, e0, e1, e2, e3;
      split2(p0, h0, e0); split2(p1, h1, e1); split2(p2, h2, e2); split2(p3, h3, e3);
      pah0 = (bf16x4){(short)h0, (short)h1, (short)h2, (short)h3};
      pal0 = (bf16x4){(short)e0, (short)e1, (short)e2, (short)e3};
    }
    {
      float t = fmaxf(fmaxf(st1[0], st1[1]), fmaxf(st1[2], st1[3]));
      t = fmaxf(t, __shfl_xor(t, 16));
      t = fmaxf(t, __shfl_xor(t, 32));
      mn1 = fmaxf(m1, t);
      al1 = __expf(m1 - mn1);
      float p0 = __expf(st1[0] - mn1), p1 = __expf(st1[1] - mn1);
      float p2 = __expf(st1[2] - mn1), p3 = __expf(st1[3] - mn1);
      float ps = (p0 + p1) + (p2 + p3);
      ps += __shfl_xor(ps, 16);
      ps += __shfl_xor(ps, 32);
      l1 = l1 * al1 + ps;
      unsigned short h0, h1, h2, h3, e0, e1, e2, e3;
      split2(p0, h0, e0); split2(p1, h1, e1); split2(p2, h2, e2); split2(p3, h3, e3);
      pah1 = (bf16x4){(short)h0, (short)h1, (short)h2, (short)h3};
      pal1 = (bf16x4){(short)e0, (short)e1, (short)e2, (short)e3};
    }

    // ---- rescale O (skip when the running max didn't move for any lane)
    if (__any(mn0 > m0)) {
      float a0 = __shfl(al0, (quad << 2) + 0);
      float a1 = __shfl(al0, (quad << 2) + 1);
      float a2 = __shfl(al0, (quad << 2) + 2);
      float a3 = __shfl(al0, (quad << 2) + 3);
#pragma unroll
      for (int ct = 0; ct < 16; ++ct) {
        o0[ct][0] *= a0; o0[ct][1] *= a1; o0[ct][2] *= a2; o0[ct][3] *= a3;
      }
    }
    if (__any(mn1 > m1)) {
      float a0 = __shfl(al1, (quad << 2) + 0);
      float a1 = __shfl(al1, (quad << 2) + 1);
      float a2 = __shfl(al1, (quad << 2) + 2);
      float a3 = __shfl(al1, (quad << 2) + 3);
#pragma unroll
      for (int ct = 0; ct < 16; ++ct) {
        o1[ct][0] *= a0; o1[ct][1] *= a1; o1[ct][2] *= a2; o1[ct][3] *= a3;
      }
    }
    m0 = mn0;  m1 = mn1;

    // ---- PV: O += P @ V, V frags shared across q-subtiles
    const unsigned char* Vb = Kb + 16384;
#pragma unroll
    for (int ct = 0; ct < 16; ++ct) {
      bf16x4 bvh = *(const bf16x4*)(Vb + (ct * 2 + 0) * 512 + laneV);
      bf16x4 bvl = *(const bf16x4*)(Vb + (ct * 2 + 1) * 512 + laneV);
      o0[ct] = MFMA16(pah0, bvh, o0[ct]);
      o0[ct] = MFMA16(pah0, bvl, o0[ct]);
      o0[ct] = MFMA16(pal0, bvh, o0[ct]);
      o1[ct] = MFMA16(pah1, bvh, o1[ct]);
      o1[ct] = MFMA16(pah1, bvl, o1[ct]);
      o1[ct] = MFMA16(pal1, bvh, o1[ct]);
    }
  }

  // ---- store unnormalized partials + (m,l)
  float* Od = (kz == 0) ? Xp : Op;
#pragma unroll
  for (int r = 0; r < 4; ++r) {
    const size_t r0off = (size_t)(grow + quad * 4 + r) * 256 + l15;
    const size_t r1off = (size_t)(grow + 16 + quad * 4 + r) * 256 + l15;
#pragma unroll
    for (int ct = 0; ct < 16; ++ct) {
      Od[r0off + ct * 16] = o0[ct][r];
      Od[r1off + ct * 16] = o1[ct][r];
    }
  }
  if (lane < 16) {
    Mp[kz * NROWS + grow + l15] = m0;
    Lp[kz * NROWS + grow + l15] = l0;
    Mp[kz * NROWS + grow + 16 + l15] = m1;
    Lp[kz * NROWS + grow + 16 + l15] = l1;
  }
}

// ---------------------------------------------------------------------------
// Split-K merge (unchanged)
// ---------------------------------------------------------------------------
__global__ __launch_bounds__(256)
void merge_kernel(const float* __restrict__ Op, const float* __restrict__ Mp,
                  const float* __restrict__ Lp, float* __restrict__ X)
{
  int idx = blockIdx.x * 256 + threadIdx.x;
  int row = idx >> 6;
  int c4  = idx & 63;
  float m0 = Mp[row], m1 = Mp[NROWS + row];
  float l0 = Lp[row], l1 = Lp[NROWS + row];
  float mm = fmaxf(m0, m1);
  float w0 = __expf(m0 - mm), w1 = __expf(m1 - mm);
  float inv = 1.0f / (w0 * l0 + w1 * l1);
  float4 x0 = ((const float4*)X)[(size_t)row * 64 + c4];
  float4 x1 = ((const float4*)Op)[(size_t)row * 64 + c4];
  float4 r;
  r.x = (w0 * x0.x + w1 * x1.x) * inv;
  r.y = (w0 * x0.y + w1 * x1.y) * inv;
  r.z = (w0 * x0.z + w1 * x1.z) * inv;
  r.w = (w0 * x0.w + w1 * x1.w) * inv;
  ((float4*)X)[(size_t)row * 64 + c4] = r;
}

// ---------------------------------------------------------------------------
extern "C" void kernel_launch(void* const* d_in, const int* in_sizes, int n_in,
                              void* d_out, int out_size, void* d_ws, size_t ws_size,
                              hipStream_t stream)
{
  const float* inp = (const float*)d_in[0];
  const float* wq  = (const float*)d_in[1];
  const float* bq  = (const float*)d_in[2];
  const float* wk  = (const float*)d_in[3];
  const float* bk  = (const float*)d_in[4];
  const float* wv  = (const float*)d_in[5];
  const float* bv  = (const float*)d_in[6];
  const float* wo  = (const float*)d_in[7];
  const float* bo  = (const float*)d_in[8];
  float* out = (float*)d_out;

  const size_t NE = (size_t)NROWS * 256;
  unsigned short* Qh  = (unsigned short*)d_ws;
  unsigned short* Ql  = Qh + NE;
  unsigned short* Kh  = Ql + NE;
  unsigned short* Kl  = Kh + NE;
  unsigned short* Vth = Kl + NE;
  unsigned short* Vtl = Vth + NE;
  float* Op = (float*)(Vtl + NE);
  float* Mp = Op + NE;
  float* Lp = Mp + 2 * NROWS;

  qkv_split_kernel<<<dim3(NROWS / 64, 3), 256, 0, stream>>>(
      inp, wq, bq, wk, bk, wv, bv, Qh, Ql, Kh, Kl, Vth, Vtl);

  attn3_kernel<<<256, 256, 0, stream>>>(Qh, Ql, Kh, Kl, Vth, Vtl, out, Op, Mp, Lp);

  merge_kernel<<<NROWS * 64 / 256, 256, 0, stream>>>(Op, Mp, Lp, out);

  oproj_kernel<<<NROWS / 64, 256, 0, stream>>>(wo, bo, out);
}

// Round 5
// 392.394 us; speedup vs baseline: 2.2249x; 2.2249x over previous
//
#include <hip/hip_runtime.h>

typedef _Float16 f16;
typedef _Float16 f16x8 __attribute__((ext_vector_type(8)));
typedef _Float16 f16x4 __attribute__((ext_vector_type(4)));
typedef float f32x4  __attribute__((ext_vector_type(4)));

#define MFMAH(a, b, c) __builtin_amdgcn_mfma_f32_16x16x32_f16(a, b, c, 0, 0, 0)

constexpr int D = 256;
constexpr int S = 4096;
constexpr int BATCH = 4;
constexpr int NROWS = BATCH * S;           // 16384
constexpr float SCALE = 0.0625f;           // 1/sqrt(256)
constexpr size_t NE = (size_t)NROWS * D;   // 4.19M elems

// ---------------- async global->LDS (gfx950), dest = uniform base + lane*16
__device__ __forceinline__ void gll16(const void* g, void* l) {
  __builtin_amdgcn_global_load_lds(
      (const __attribute__((address_space(1))) unsigned int*)g,
      (__attribute__((address_space(3))) unsigned int*)l, 16, 0, 0);
}

// ---------------------------------------------------------------------------
// QKV projection: fp32 GEMM -> fp16 outputs.
// Q scaled by 1/16. V written key-PERMUTED + transposed: within each 32-key
// group, pos = quad*8 + t*4 + r  <->  key = t*16 + quad*4 + r, so the PV
// B-fragment (k = quad*8 + j) is 16B-contiguous in global for gll16 staging.
// ---------------------------------------------------------------------------
__global__ __launch_bounds__(256)
void qkv_f16_kernel(const float* __restrict__ in,
                    const float* __restrict__ wq, const float* __restrict__ bq,
                    const float* __restrict__ wk, const float* __restrict__ bk,
                    const float* __restrict__ wv, const float* __restrict__ bv,
                    f16* __restrict__ Qh, f16* __restrict__ Kh, f16* __restrict__ Vp)
{
  const int m = blockIdx.y;
  const float* W    = (m == 0) ? wq : (m == 1) ? wk : wv;
  const float* bias = (m == 0) ? bq : (m == 1) ? bk : bv;
  const int rb = blockIdx.x * 64;
  const int col_off = m * D;

  __shared__ float xs[64][256];
  const int tid = threadIdx.x;
#pragma unroll
  for (int it = 0; it < 16; ++it) {
    int f4 = it * 256 + tid;
    int row = f4 >> 6;
    int c4 = (f4 & 63) << 2;
    *(float4*)&xs[row][c4] =
        *(const float4*)(in + (size_t)(rb + row) * (3 * D) + col_off + c4);
  }
  __syncthreads();

  const int c0 = (tid & 31) * 8;
  const int r0 = (tid >> 5) * 8;
  float acc[8][8];
#pragma unroll
  for (int rr = 0; rr < 8; ++rr)
#pragma unroll
    for (int cc = 0; cc < 8; ++cc) acc[rr][cc] = 0.0f;

  for (int i4 = 0; i4 < 64; ++i4) {
    float4 x4[8];
#pragma unroll
    for (int rr = 0; rr < 8; ++rr)
      x4[rr] = *(const float4*)&xs[r0 + rr][i4 * 4];
#pragma unroll
    for (int di = 0; di < 4; ++di) {
      const float* wrow = W + (size_t)(i4 * 4 + di) * 256 + c0;
      float4 w0 = *(const float4*)(wrow);
      float4 w1 = *(const float4*)(wrow + 4);
#pragma unroll
      for (int rr = 0; rr < 8; ++rr) {
        float xv = (di == 0) ? x4[rr].x
                 : (di == 1) ? x4[rr].y
                 : (di == 2) ? x4[rr].z : x4[rr].w;
        acc[rr][0] += xv * w0.x;  acc[rr][1] += xv * w0.y;
        acc[rr][2] += xv * w0.z;  acc[rr][3] += xv * w0.w;
        acc[rr][4] += xv * w1.x;  acc[rr][5] += xv * w1.y;
        acc[rr][6] += xv * w1.z;  acc[rr][7] += xv * w1.w;
      }
    }
  }

  float bv8[8];
#pragma unroll
  for (int cc = 0; cc < 8; ++cc) bv8[cc] = bias[c0 + cc];

  if (m < 2) {
    f16* Hd = (m == 0) ? Qh : Kh;
    const float sc = (m == 0) ? SCALE : 1.0f;
#pragma unroll
    for (int rr = 0; rr < 8; ++rr) {
      f16x8 h;
#pragma unroll
      for (int cc = 0; cc < 8; ++cc) h[cc] = (f16)((acc[rr][cc] + bv8[cc]) * sc);
      *(f16x8*)&Hd[(size_t)(rb + r0 + rr) * 256 + c0] = h;
    }
  } else {
    const int srow = rb + r0;              // 8 consecutive seq rows start
    const int b_   = srow >> 12;
    const int sq   = srow & 4095;
    const int w0   = sq & 31;              // in {0,8,16,24}
    const int t    = w0 >> 4;
    const int q    = (w0 >> 2) & 3;        // in {0,2}
    const int pos1 = q * 8 + t * 4;        // rows rr=0..3
    const int pos2 = (q + 1) * 8 + t * 4;  // rows rr=4..7
    const size_t gbase = ((size_t)(b_ * 256 + c0)) * 4096 + (sq & ~31);
#pragma unroll
    for (int cc = 0; cc < 8; ++cc) {
      f16x4 ha, hb;
#pragma unroll
      for (int rr = 0; rr < 4; ++rr) {
        ha[rr] = (f16)(acc[rr][cc] + bv8[cc]);
        hb[rr] = (f16)(acc[rr + 4][cc] + bv8[cc]);
      }
      f16* vb = Vp + gbase + (size_t)cc * 4096;
      *(f16x4*)(vb + pos1) = ha;
      *(f16x4*)(vb + pos2) = hb;
    }
  }
}

// ---------------------------------------------------------------------------
// Output projection, fp32 in-place on d_out (unchanged, known-good).
// ---------------------------------------------------------------------------
__global__ __launch_bounds__(256)
void oproj_kernel(const float* __restrict__ wo, const float* __restrict__ bo,
                  float* out)
{
  const int rb = blockIdx.x * 64;
  __shared__ float xs[64][256];
  const int tid = threadIdx.x;
#pragma unroll
  for (int it = 0; it < 16; ++it) {
    int f4 = it * 256 + tid;
    int row = f4 >> 6;
    int c4 = (f4 & 63) << 2;
    *(float4*)&xs[row][c4] = *(const float4*)(out + (size_t)(rb + row) * 256 + c4);
  }
  __syncthreads();

  const int c0 = (tid & 31) * 8;
  const int r0 = (tid >> 5) * 8;
  float acc[8][8];
#pragma unroll
  for (int rr = 0; rr < 8; ++rr)
#pragma unroll
    for (int cc = 0; cc < 8; ++cc) acc[rr][cc] = 0.0f;

  for (int i4 = 0; i4 < 64; ++i4) {
    float4 x4[8];
#pragma unroll
    for (int rr = 0; rr < 8; ++rr)
      x4[rr] = *(const float4*)&xs[r0 + rr][i4 * 4];
#pragma unroll
    for (int di = 0; di < 4; ++di) {
      const float* wrow = wo + (size_t)(i4 * 4 + di) * 256 + c0;
      float4 w0 = *(const float4*)(wrow);
      float4 w1 = *(const float4*)(wrow + 4);
#pragma unroll
      for (int rr = 0; rr < 8; ++rr) {
        float xv = (di == 0) ? x4[rr].x
                 : (di == 1) ? x4[rr].y
                 : (di == 2) ? x4[rr].z : x4[rr].w;
        acc[rr][0] += xv * w0.x;  acc[rr][1] += xv * w0.y;
        acc[rr][2] += xv * w0.z;  acc[rr][3] += xv * w0.w;
        acc[rr][4] += xv * w1.x;  acc[rr][5] += xv * w1.y;
        acc[rr][6] += xv * w1.z;  acc[rr][7] += xv * w1.w;
      }
    }
  }

  float4 b0 = *(const float4*)(bo + c0);
  float4 b1 = *(const float4*)(bo + c0 + 4);
#pragma unroll
  for (int rr = 0; rr < 8; ++rr) {
    float4 v0, v1;
    v0.x = acc[rr][0] + b0.x; v0.y = acc[rr][1] + b0.y;
    v0.z = acc[rr][2] + b0.z; v0.w = acc[rr][3] + b0.w;
    v1.x = acc[rr][4] + b1.x; v1.y = acc[rr][5] + b1.y;
    v1.z = acc[rr][6] + b1.z; v1.w = acc[rr][7] + b1.w;
    float* op = out + (size_t)(rb + r0 + rr) * 256 + c0;
    *(float4*)op = v0;
    *(float4*)(op + 4) = v1;
  }
}

// ---------------------------------------------------------------------------
// fp16 MFMA flash attention v5. 256 blocks x 512 thr (8 waves, Tq=32/wave).
// combo = bx&15 -> (b = combo&3, kz = combo>>2); qb = bx>>4 in [0,16).
// Split-K=4 (1024 keys per kz), 32-key tiles, 32 iterations.
// QK: 1-pass fp16 16x16x32 (S^T = K.Q^T). PV: 1-pass fp16 16x16x32 over 32
// perm-packed keys. LDS 2 x 32KB double buffer; all reads b128 lane-linear
// (conflict-free, validated r4); staging via global_load_lds issued AFTER the
// barrier so it drains one full iteration later (fully hidden).
// ---------------------------------------------------------------------------
__global__ __launch_bounds__(512, 2)
void attn5_kernel(const f16* __restrict__ Qh, const f16* __restrict__ Kh,
                  const f16* __restrict__ Vp,
                  float* __restrict__ Xp, f16* __restrict__ Pp,
                  float* __restrict__ Mp, float* __restrict__ Lp)
{
  // per 32KB buffer: K frag (t,kc) at (t*8+kc)*1024 ; V frag ct at 16384+ct*1024
  __shared__ __align__(16) char KVs[2][32768];

  const int tid  = threadIdx.x;
  const int lane = tid & 63;
  const int w    = tid >> 6;       // wave 0..7
  const int l15  = lane & 15;
  const int quad = lane >> 4;

  const int bx    = blockIdx.x;
  const int combo = bx & 15;
  const int b     = combo & 3;
  const int kz    = combo >> 2;
  const int qb    = bx >> 4;                  // 0..15
  const int qrow0 = qb * 256 + w * 32;        // within batch
  const int grow  = b * 4096 + qrow0;         // global row
  const int k0    = kz * 1024;

  // ---- resident Q B-fragments (n = q = l15, k = quad*8+j per kc)
  f16x8 qf[2][8];
#pragma unroll
  for (int sub = 0; sub < 2; ++sub) {
    const size_t qoff = (size_t)(grow + sub * 16 + l15) * 256 + quad * 8;
#pragma unroll
    for (int kc = 0; kc < 8; ++kc)
      qf[sub][kc] = *(const f16x8*)(Qh + qoff + kc * 32);
  }

  // ---- staging: wave w stages K frags f=2w,2w+1 and V frags ct=2w,2w+1
  const f16* kg[2];
  const f16* vg[2];
  int kld[2], vld[2];
#pragma unroll
  for (int i = 0; i < 2; ++i) {
    int f = 2 * w + i;              // 0..15
    int t = f >> 3, kc = f & 7;
    kg[i]  = Kh + (size_t)(b * 4096 + k0 + t * 16 + l15) * 256 + kc * 32 + quad * 8;
    kld[i] = f * 1024;
    vg[i]  = Vp + (size_t)(b * 256 + f * 16 + l15) * 4096 + k0 + quad * 8;
    vld[i] = 16384 + f * 1024;
  }
  auto stage = [&](int buf) {
    char* base = &KVs[buf][0];
    gll16(kg[0], base + kld[0]);
    gll16(kg[1], base + kld[1]);
    gll16(vg[0], base + vld[0]);
    gll16(vg[1], base + vld[1]);
    kg[0] += 32 * 256;  kg[1] += 32 * 256;
    vg[0] += 32;        vg[1] += 32;
  };

  f32x4 o0[16], o1[16];
#pragma unroll
  for (int ct = 0; ct < 16; ++ct) {
    o0[ct] = (f32x4){0.f, 0.f, 0.f, 0.f};
    o1[ct] = (f32x4){0.f, 0.f, 0.f, 0.f};
  }
  float m0 = -3.0e38f, m1 = -3.0e38f, l0 = 0.f, l1 = 0.f;

  stage(0);

  for (int it = 0; it < 32; ++it) {
    __syncthreads();                 // staging for tile `it` complete
    if (it < 31) stage((it + 1) & 1);
    const char* Bf = &KVs[it & 1][0];

    // ---- QK: S^T[key][q], 1-pass fp16, tiles A (keys 0-15) and B (16-31)
    f32x4 sA0 = (f32x4){0.f,0.f,0.f,0.f}, sB0 = (f32x4){0.f,0.f,0.f,0.f};
    f32x4 sA1 = (f32x4){0.f,0.f,0.f,0.f}, sB1 = (f32x4){0.f,0.f,0.f,0.f};
#pragma unroll
    for (int kc = 0; kc < 8; ++kc) {
      f16x8 kA = *(const f16x8*)(Bf + kc * 1024 + lane * 16);
      f16x8 kB = *(const f16x8*)(Bf + 8192 + kc * 1024 + lane * 16);
      sA0 = MFMAH(kA, qf[0][kc], sA0);
      sA1 = MFMAH(kA, qf[1][kc], sA1);
      sB0 = MFMAH(kB, qf[0][kc], sB0);
      sB1 = MFMAH(kB, qf[1][kc], sB1);
    }

    // ---- online softmax over 32 keys per q-subtile (lane: q=l15, keys quad*4+r)
    float mn0, mn1, al0, al1;
    f16x8 ph0, ph1;
    {
      float t = fmaxf(fmaxf(fmaxf(sA0[0], sA0[1]), fmaxf(sA0[2], sA0[3])),
                      fmaxf(fmaxf(sB0[0], sB0[1]), fmaxf(sB0[2], sB0[3])));
      t = fmaxf(t, __shfl_xor(t, 16));
      t = fmaxf(t, __shfl_xor(t, 32));
      mn0 = fmaxf(m0, t);
      al0 = __expf(m0 - mn0);
      float ps = 0.f;
#pragma unroll
      for (int r = 0; r < 4; ++r) {
        float pa = __expf(sA0[r] - mn0);
        float pb = __expf(sB0[r] - mn0);
        ph0[r] = (f16)pa;
        ph0[r + 4] = (f16)pb;
        ps += pa + pb;
      }
      ps += __shfl_xor(ps, 16);
      ps += __shfl_xor(ps, 32);
      l0 = l0 * al0 + ps;
    }
    {
      float t = fmaxf(fmaxf(fmaxf(sA1[0], sA1[1]), fmaxf(sA1[2], sA1[3])),
                      fmaxf(fmaxf(sB1[0], sB1[1]), fmaxf(sB1[2], sB1[3])));
      t = fmaxf(t, __shfl_xor(t, 16));
      t = fmaxf(t, __shfl_xor(t, 32));
      mn1 = fmaxf(m1, t);
      al1 = __expf(m1 - mn1);
      float ps = 0.f;
#pragma unroll
      for (int r = 0; r < 4; ++r) {
        float pa = __expf(sA1[r] - mn1);
        float pb = __expf(sB1[r] - mn1);
        ph1[r] = (f16)pa;
        ph1[r + 4] = (f16)pb;
        ps += pa + pb;
      }
      ps += __shfl_xor(ps, 16);
      ps += __shfl_xor(ps, 32);
      l1 = l1 * al1 + ps;
    }

    // ---- rescale O when running max moved (O rows q = quad*4+r)
    if (__any(mn0 > m0)) {
      float a0 = __shfl(al0, (quad << 2) + 0);
      float a1 = __shfl(al0, (quad << 2) + 1);
      float a2 = __shfl(al0, (quad << 2) + 2);
      float a3 = __shfl(al0, (quad << 2) + 3);
#pragma unroll
      for (int ct = 0; ct < 16; ++ct) {
        o0[ct][0] *= a0; o0[ct][1] *= a1; o0[ct][2] *= a2; o0[ct][3] *= a3;
      }
    }
    if (__any(mn1 > m1)) {
      float a0 = __shfl(al1, (quad << 2) + 0);
      float a1 = __shfl(al1, (quad << 2) + 1);
      float a2 = __shfl(al1, (quad << 2) + 2);
      float a3 = __shfl(al1, (quad << 2) + 3);
#pragma unroll
      for (int ct = 0; ct < 16; ++ct) {
        o1[ct][0] *= a0; o1[ct][1] *= a1; o1[ct][2] *= a2; o1[ct][3] *= a3;
      }
    }
    m0 = mn0;  m1 = mn1;

    // ---- PV: O += P @ V over 32 perm-packed keys, 1-pass fp16
#pragma unroll
    for (int ct = 0; ct < 16; ++ct) {
      f16x8 vf = *(const f16x8*)(Bf + 16384 + ct * 1024 + lane * 16);
      o0[ct] = MFMAH(ph0, vf, o0[ct]);
      o1[ct] = MFMAH(ph1, vf, o1[ct]);
    }
  }

  // ---- store unnormalized partials + (m,l); kz0 -> fp32 d_out, else fp16 ws
  if (kz == 0) {
#pragma unroll
    for (int r = 0; r < 4; ++r) {
      const size_t ro0 = (size_t)(grow + quad * 4 + r) * 256 + l15;
      const size_t ro1 = (size_t)(grow + 16 + quad * 4 + r) * 256 + l15;
#pragma unroll
      for (int ct = 0; ct < 16; ++ct) {
        Xp[ro0 + ct * 16] = o0[ct][r];
        Xp[ro1 + ct * 16] = o1[ct][r];
      }
    }
  } else {
    f16* Od = Pp + (size_t)(kz - 1) * NE;
#pragma unroll
    for (int r = 0; r < 4; ++r) {
      const size_t ro0 = (size_t)(grow + quad * 4 + r) * 256 + l15;
      const size_t ro1 = (size_t)(grow + 16 + quad * 4 + r) * 256 + l15;
#pragma unroll
      for (int ct = 0; ct < 16; ++ct) {
        Od[ro0 + ct * 16] = (f16)o0[ct][r];
        Od[ro1 + ct * 16] = (f16)o1[ct][r];
      }
    }
  }
  if (lane < 16) {
    Mp[kz * NROWS + grow + l15] = m0;
    Lp[kz * NROWS + grow + l15] = l0;
    Mp[kz * NROWS + grow + 16 + l15] = m1;
    Lp[kz * NROWS + grow + 16 + l15] = l1;
  }
}

// ---------------------------------------------------------------------------
// 4-way split-K merge: x = sum_z w_z O_z / sum_z w_z l_z  (in-place on d_out)
// ---------------------------------------------------------------------------
__global__ __launch_bounds__(256)
void merge4_kernel(const f16* __restrict__ Pp, const float* __restrict__ Mp,
                   const float* __restrict__ Lp, float* __restrict__ X)
{
  int idx = blockIdx.x * 256 + threadIdx.x;   // float4 groups, NROWS*64 total
  int row = idx >> 6;
  int c4  = idx & 63;
  float m[4], l[4];
#pragma unroll
  for (int z = 0; z < 4; ++z) { m[z] = Mp[z * NROWS + row]; l[z] = Lp[z * NROWS + row]; }
  float mm = fmaxf(fmaxf(m[0], m[1]), fmaxf(m[2], m[3]));
  float wz[4], denom = 0.f;
#pragma unroll
  for (int z = 0; z < 4; ++z) { wz[z] = __expf(m[z] - mm); denom += wz[z] * l[z]; }
  float inv = 1.0f / denom;

  float4 x0 = ((const float4*)X)[(size_t)row * 64 + c4];
  float ax = wz[0] * x0.x, ay = wz[0] * x0.y, az = wz[0] * x0.z, aw = wz[0] * x0.w;
#pragma unroll
  for (int z = 1; z < 4; ++z) {
    f16x4 h = *(const f16x4*)(Pp + (size_t)(z - 1) * NE + (size_t)row * 256 + c4 * 4);
    ax += wz[z] * (float)h[0];
    ay += wz[z] * (float)h[1];
    az += wz[z] * (float)h[2];
    aw += wz[z] * (float)h[3];
  }
  float4 r;
  r.x = ax * inv; r.y = ay * inv; r.z = az * inv; r.w = aw * inv;
  ((float4*)X)[(size_t)row * 64 + c4] = r;
}

// ---------------------------------------------------------------------------
extern "C" void kernel_launch(void* const* d_in, const int* in_sizes, int n_in,
                              void* d_out, int out_size, void* d_ws, size_t ws_size,
                              hipStream_t stream)
{
  const float* inp = (const float*)d_in[0];
  const float* wq  = (const float*)d_in[1];
  const float* bq  = (const float*)d_in[2];
  const float* wk  = (const float*)d_in[3];
  const float* bk  = (const float*)d_in[4];
  const float* wv  = (const float*)d_in[5];
  const float* bv  = (const float*)d_in[6];
  const float* wo  = (const float*)d_in[7];
  const float* bo  = (const float*)d_in[8];
  float* out = (float*)d_out;

  // workspace (~51 MB): Qh,Kh,Vp fp16 + 3 fp16 partials + m/l
  f16* Qh = (f16*)d_ws;
  f16* Kh = Qh + NE;
  f16* Vp = Kh + NE;
  f16* Pp = Vp + NE;                       // 3*NE (kz=1..3 partials)
  float* Mp = (float*)(Pp + 3 * NE);       // 4*NROWS
  float* Lp = Mp + 4 * NROWS;              // 4*NROWS

  qkv_f16_kernel<<<dim3(NROWS / 64, 3), 256, 0, stream>>>(
      inp, wq, bq, wk, bk, wv, bv, Qh, Kh, Vp);

  attn5_kernel<<<256, 512, 0, stream>>>(Qh, Kh, Vp, out, Pp, Mp, Lp);

  merge4_kernel<<<NROWS * 64 / 256, 256, 0, stream>>>(Pp, Mp, Lp, out);

  oproj_kernel<<<NROWS / 64, 256, 0, stream>>>(wo, bo, out);
}

// Round 6
// 302.152 us; speedup vs baseline: 2.8895x; 1.2987x over previous
//
#include <hip/hip_runtime.h>

typedef _Float16 f16;
typedef _Float16 f16x4 __attribute__((ext_vector_type(4)));
typedef _Float16 f16x8 __attribute__((ext_vector_type(8)));
typedef float f32x4  __attribute__((ext_vector_type(4)));

#define MFMAH(a, b, c) __builtin_amdgcn_mfma_f32_16x16x32_f16(a, b, c, 0, 0, 0)

constexpr int D = 256;
constexpr int S = 4096;
constexpr int BATCH = 4;
constexpr int NROWS = BATCH * S;           // 16384
constexpr float SCALE = 0.0625f;           // 1/sqrt(256)
constexpr size_t NE = (size_t)NROWS * D;   // 4.19M elems

// async global->LDS: per-lane src addr, wave-uniform LDS base (+lane*16 by HW)
__device__ __forceinline__ void gll16(const void* g, void* l) {
  __builtin_amdgcn_global_load_lds(
      (const __attribute__((address_space(1))) unsigned int*)g,
      (__attribute__((address_space(3))) unsigned int*)l, 16, 0, 0);
}

// ---------------------------------------------------------------------------
// Prep: Wt[m][n][k] = w_m[k][n] as fp16 (transposed for MFMA B-fragments).
// ---------------------------------------------------------------------------
__global__ __launch_bounds__(256)
void prep_wt_kernel(const float* __restrict__ wq, const float* __restrict__ wk,
                    const float* __restrict__ wv, const float* __restrict__ wo,
                    f16* __restrict__ Wt)
{
  const int m = blockIdx.y;
  const float* w = (m == 0) ? wq : (m == 1) ? wk : (m == 2) ? wv : wo;
  int id = blockIdx.x * 256 + threadIdx.x;    // 0..65535
  int k = id >> 8, n = id & 255;
  Wt[((size_t)m << 16) + n * 256 + k] = (f16)w[k * 256 + n];
}

// ---------------------------------------------------------------------------
// QKV projection via MFMA. Block = 64 rows of one matrix m; wave = 16 rows.
// A-frag: input rows fp32->fp16 on the fly. B-frag: Wt fp16 (L2-resident).
// Outputs: Q row-major (scaled); K,V in frag-contiguous layouts:
//   Kf frag(g=key>>4, kc): [dgroup 0..3][key16][8 d]  (1KB, gll16-ready)
//   Vf frag(gv=key>>5, ct): [pg 0..3][dim16][8 pos]   (1KB), pos = perm(key)
//   perm: pos = ((k>>2)&3)*8 + ((k>>4)&1)*4 + (k&3)   (validated in r5 PV)
// ---------------------------------------------------------------------------
__global__ __launch_bounds__(256)
void qkv_mfma_kernel(const float* __restrict__ in, const f16* __restrict__ Wt,
                     const float* __restrict__ bq, const float* __restrict__ bk,
                     const float* __restrict__ bv,
                     f16* __restrict__ Qh, f16* __restrict__ Kf, f16* __restrict__ Vf)
{
  const int m = blockIdx.y;
  const int tid = threadIdx.x, lane = tid & 63, w = tid >> 6;
  const int l15 = lane & 15, quad = lane >> 4;
  const int row0 = blockIdx.x * 64 + w * 16;
  const f16* Wm = Wt + ((size_t)m << 16);
  const float* bias = (m == 0) ? bq : (m == 1) ? bk : bv;

  f32x4 acc[16];
#pragma unroll
  for (int ct = 0; ct < 16; ++ct) acc[ct] = (f32x4){0.f, 0.f, 0.f, 0.f};

  const float* arow = in + (size_t)(row0 + l15) * 768 + m * 256 + quad * 8;
#pragma unroll
  for (int kc = 0; kc < 8; ++kc) {
    float4 a0 = *(const float4*)(arow + kc * 32);
    float4 a1 = *(const float4*)(arow + kc * 32 + 4);
    f16x8 a;
    a[0] = (f16)a0.x; a[1] = (f16)a0.y; a[2] = (f16)a0.z; a[3] = (f16)a0.w;
    a[4] = (f16)a1.x; a[5] = (f16)a1.y; a[6] = (f16)a1.z; a[7] = (f16)a1.w;
#pragma unroll
    for (int ct = 0; ct < 16; ++ct) {
      f16x8 b = *(const f16x8*)(Wm + (ct * 16 + l15) * 256 + kc * 32 + quad * 8);
      acc[ct] = MFMAH(a, b, acc[ct]);
    }
  }

  if (m == 0) {
#pragma unroll
    for (int ct = 0; ct < 16; ++ct) {
      float bct = bias[ct * 16 + l15];
#pragma unroll
      for (int r = 0; r < 4; ++r) {
        float v = (acc[ct][r] + bct) * SCALE;
        Qh[(size_t)(row0 + quad * 4 + r) * 256 + ct * 16 + l15] = (f16)v;
      }
    }
  } else if (m == 1) {
#pragma unroll
    for (int ct = 0; ct < 16; ++ct) {
      float bct = bias[ct * 16 + l15];
      int col = ct * 16 + l15;
#pragma unroll
      for (int r = 0; r < 4; ++r) {
        int row = row0 + quad * 4 + r;
        int b_ = row >> 12, key = row & 4095;
        size_t frag = ((size_t)(b_ * 256 + (key >> 4))) * 8 + (col >> 5);
        int off = ((col & 31) >> 3) * 128 + (key & 15) * 8 + (col & 7);
        Kf[frag * 512 + off] = (f16)(acc[ct][r] + bct);
      }
    }
  } else {
#pragma unroll
    for (int ct = 0; ct < 16; ++ct) {
      float bct = bias[ct * 16 + l15];
      int col = ct * 16 + l15;        // dim
#pragma unroll
      for (int r = 0; r < 4; ++r) {
        int row = row0 + quad * 4 + r;
        int b_ = row >> 12, sq = row & 4095;
        int gv = sq >> 5, ksq = sq & 31;
        int pos = ((ksq >> 2) & 3) * 8 + ((ksq >> 4) & 1) * 4 + (ksq & 3);
        size_t frag = ((size_t)(b_ * 128 + gv)) * 16 + (col >> 4);
        int off = (pos >> 3) * 128 + (col & 15) * 8 + (pos & 7);
        Vf[frag * 512 + off] = (f16)(acc[ct][r] + bct);
      }
    }
  }
}

// ---------------------------------------------------------------------------
// fp16 MFMA flash attention v6. 512 blocks x 256 thr (4 waves, Tq=32/wave)
// -> 2 blocks/CU (independent barriers). combo = bx&15 -> (b=combo&3,
// kz=combo>>2); qb = bx>>4 in [0,32). Split-K=4, 32-key tiles, 32 iters.
// Staging: 32 contiguous 1KB frags per tile via gll16 (8 per wave).
// ---------------------------------------------------------------------------
__global__ __launch_bounds__(256, 2)
void attn6_kernel(const f16* __restrict__ Qh, const char* __restrict__ Kf,
                  const char* __restrict__ Vf,
                  f16* __restrict__ Pp, float* __restrict__ Mp, float* __restrict__ Lp)
{
  __shared__ __align__(16) char KVs[2][32768];   // [K 16 frags][V 16 frags]

  const int tid = threadIdx.x, lane = tid & 63, w = tid >> 6;
  const int l15 = lane & 15, quad = lane >> 4;

  const int bx    = blockIdx.x;
  const int combo = bx & 15;
  const int b     = combo & 3;
  const int kz    = combo >> 2;
  const int qb    = bx >> 4;                   // 0..31
  const int qrow0 = qb * 128 + w * 32;
  const int grow  = b * 4096 + qrow0;

  // resident Q B-fragments (n=q=l15, k=quad*8+j per kc)
  f16x8 qf[2][8];
#pragma unroll
  for (int sub = 0; sub < 2; ++sub) {
    const size_t qoff = (size_t)(grow + sub * 16 + l15) * 256 + quad * 8;
#pragma unroll
    for (int kc = 0; kc < 8; ++kc)
      qf[sub][kc] = *(const f16x8*)(Qh + qoff + kc * 32);
  }

  // staging: wave w stages K frags f=4w..4w+3 and V frags f=4w..4w+3
  const char* kg[4];
  const char* vg[4];
#pragma unroll
  for (int i = 0; i < 4; ++i) {
    int f = 4 * w + i;
    kg[i] = Kf + (((size_t)(b * 256 + kz * 64 + (f >> 3))) * 8 + (f & 7)) * 1024
               + lane * 16;
    vg[i] = Vf + (((size_t)(b * 128 + kz * 32)) * 16 + f) * 1024 + lane * 16;
  }
  auto stage = [&](int buf) {
    char* base = &KVs[buf][0];
#pragma unroll
    for (int i = 0; i < 4; ++i) { gll16(kg[i], base + (4 * w + i) * 1024); kg[i] += 16384; }
#pragma unroll
    for (int i = 0; i < 4; ++i) { gll16(vg[i], base + 16384 + (4 * w + i) * 1024); vg[i] += 16384; }
  };

  f32x4 o0[16], o1[16];
#pragma unroll
  for (int ct = 0; ct < 16; ++ct) {
    o0[ct] = (f32x4){0.f, 0.f, 0.f, 0.f};
    o1[ct] = (f32x4){0.f, 0.f, 0.f, 0.f};
  }
  float m0 = -3.0e38f, m1 = -3.0e38f, l0 = 0.f, l1 = 0.f;

  stage(0);

  for (int it = 0; it < 32; ++it) {
    __syncthreads();
    if (it < 31) stage((it + 1) & 1);
    const char* Bf = &KVs[it & 1][0];

    // QK: S^T[key][q], keys 0-15 (A) and 16-31 (B)
    f32x4 sA0 = (f32x4){0.f,0.f,0.f,0.f}, sB0 = (f32x4){0.f,0.f,0.f,0.f};
    f32x4 sA1 = (f32x4){0.f,0.f,0.f,0.f}, sB1 = (f32x4){0.f,0.f,0.f,0.f};
#pragma unroll
    for (int kc = 0; kc < 8; ++kc) {
      f16x8 kA = *(const f16x8*)(Bf + kc * 1024 + lane * 16);
      f16x8 kB = *(const f16x8*)(Bf + 8192 + kc * 1024 + lane * 16);
      sA0 = MFMAH(kA, qf[0][kc], sA0);
      sA1 = MFMAH(kA, qf[1][kc], sA1);
      sB0 = MFMAH(kB, qf[0][kc], sB0);
      sB1 = MFMAH(kB, qf[1][kc], sB1);
    }

    // online softmax (lane: q=l15; keys quad*4+r in each 16-tile)
    float mn0, mn1, al0, al1;
    f16x8 ph0, ph1;
    {
      float t = fmaxf(fmaxf(fmaxf(sA0[0], sA0[1]), fmaxf(sA0[2], sA0[3])),
                      fmaxf(fmaxf(sB0[0], sB0[1]), fmaxf(sB0[2], sB0[3])));
      t = fmaxf(t, __shfl_xor(t, 16));
      t = fmaxf(t, __shfl_xor(t, 32));
      mn0 = fmaxf(m0, t);
      al0 = __expf(m0 - mn0);
      float ps = 0.f;
#pragma unroll
      for (int r = 0; r < 4; ++r) {
        float pa = __expf(sA0[r] - mn0);
        float pb = __expf(sB0[r] - mn0);
        ph0[r] = (f16)pa;  ph0[r + 4] = (f16)pb;
        ps += pa + pb;
      }
      ps += __shfl_xor(ps, 16);
      ps += __shfl_xor(ps, 32);
      l0 = l0 * al0 + ps;
    }
    {
      float t = fmaxf(fmaxf(fmaxf(sA1[0], sA1[1]), fmaxf(sA1[2], sA1[3])),
                      fmaxf(fmaxf(sB1[0], sB1[1]), fmaxf(sB1[2], sB1[3])));
      t = fmaxf(t, __shfl_xor(t, 16));
      t = fmaxf(t, __shfl_xor(t, 32));
      mn1 = fmaxf(m1, t);
      al1 = __expf(m1 - mn1);
      float ps = 0.f;
#pragma unroll
      for (int r = 0; r < 4; ++r) {
        float pa = __expf(sA1[r] - mn1);
        float pb = __expf(sB1[r] - mn1);
        ph1[r] = (f16)pa;  ph1[r + 4] = (f16)pb;
        ps += pa + pb;
      }
      ps += __shfl_xor(ps, 16);
      ps += __shfl_xor(ps, 32);
      l1 = l1 * al1 + ps;
    }

    if (__any(mn0 > m0)) {
      float a0 = __shfl(al0, (quad << 2) + 0);
      float a1 = __shfl(al0, (quad << 2) + 1);
      float a2 = __shfl(al0, (quad << 2) + 2);
      float a3 = __shfl(al0, (quad << 2) + 3);
#pragma unroll
      for (int ct = 0; ct < 16; ++ct) {
        o0[ct][0] *= a0; o0[ct][1] *= a1; o0[ct][2] *= a2; o0[ct][3] *= a3;
      }
    }
    if (__any(mn1 > m1)) {
      float a0 = __shfl(al1, (quad << 2) + 0);
      float a1 = __shfl(al1, (quad << 2) + 1);
      float a2 = __shfl(al1, (quad << 2) + 2);
      float a3 = __shfl(al1, (quad << 2) + 3);
#pragma unroll
      for (int ct = 0; ct < 16; ++ct) {
        o1[ct][0] *= a0; o1[ct][1] *= a1; o1[ct][2] *= a2; o1[ct][3] *= a3;
      }
    }
    m0 = mn0;  m1 = mn1;

    // PV: O += P @ V (perm-packed 32 keys, 1-pass)
#pragma unroll
    for (int ct = 0; ct < 16; ++ct) {
      f16x8 vf = *(const f16x8*)(Bf + 16384 + ct * 1024 + lane * 16);
      o0[ct] = MFMAH(ph0, vf, o0[ct]);
      o1[ct] = MFMAH(ph1, vf, o1[ct]);
    }
  }

  // store fp16 partials + (m,l)
  f16* Od = Pp + (size_t)kz * NE;
#pragma unroll
  for (int r = 0; r < 4; ++r) {
    const size_t ro0 = (size_t)(grow + quad * 4 + r) * 256 + l15;
    const size_t ro1 = (size_t)(grow + 16 + quad * 4 + r) * 256 + l15;
#pragma unroll
    for (int ct = 0; ct < 16; ++ct) {
      Od[ro0 + ct * 16] = (f16)o0[ct][r];
      Od[ro1 + ct * 16] = (f16)o1[ct][r];
    }
  }
  if (lane < 16) {
    Mp[kz * NROWS + grow + l15] = m0;
    Lp[kz * NROWS + grow + l15] = l0;
    Mp[kz * NROWS + grow + 16 + l15] = m1;
    Lp[kz * NROWS + grow + 16 + l15] = l1;
  }
}

// ---------------------------------------------------------------------------
// Fused split-K merge + output projection (MFMA). Block = 64 rows.
// Prologue: merge 4 fp16 partials -> xs fp16 in LDS. Then x @ wo + bo -> out.
// ---------------------------------------------------------------------------
__global__ __launch_bounds__(256)
void oproj_mfma_kernel(const f16* __restrict__ Pp, const float* __restrict__ Mp,
                       const float* __restrict__ Lp, const f16* __restrict__ Wto,
                       const float* __restrict__ bo, float* __restrict__ out)
{
  __shared__ f16 xs[64][264];   // pad to 264 (stride 528B)
  const int tid = threadIdx.x, lane = tid & 63, w = tid >> 6;
  const int l15 = lane & 15, quad = lane >> 4;
  const int rb = blockIdx.x * 64;

  // ---- merge prologue: thread -> col4 = (tid&63)*4, row = rb + e*4 + (tid>>6)
  const int c4 = (tid & 63) * 4;
  const int rsub = tid >> 6;
#pragma unroll 4
  for (int e = 0; e < 16; ++e) {
    int row = rb + e * 4 + rsub;
    float m[4], l[4];
#pragma unroll
    for (int z = 0; z < 4; ++z) {
      m[z] = Mp[z * NROWS + row];
      l[z] = Lp[z * NROWS + row];
    }
    float mm = fmaxf(fmaxf(m[0], m[1]), fmaxf(m[2], m[3]));
    float wz[4], denom = 0.f;
#pragma unroll
    for (int z = 0; z < 4; ++z) { wz[z] = __expf(m[z] - mm); denom += wz[z] * l[z]; }
    float inv = 1.0f / denom;
    float s0 = 0.f, s1 = 0.f, s2 = 0.f, s3 = 0.f;
#pragma unroll
    for (int z = 0; z < 4; ++z) {
      f16x4 h = *(const f16x4*)(Pp + (size_t)z * NE + (size_t)row * 256 + c4);
      s0 += wz[z] * (float)h[0];
      s1 += wz[z] * (float)h[1];
      s2 += wz[z] * (float)h[2];
      s3 += wz[z] * (float)h[3];
    }
    f16x4 xv;
    xv[0] = (f16)(s0 * inv); xv[1] = (f16)(s1 * inv);
    xv[2] = (f16)(s2 * inv); xv[3] = (f16)(s3 * inv);
    *(f16x4*)&xs[e * 4 + rsub][c4] = xv;
  }
  __syncthreads();

  // ---- GEMM: wave w -> rows rb+16w..+16
  f32x4 acc[16];
#pragma unroll
  for (int ct = 0; ct < 16; ++ct) acc[ct] = (f32x4){0.f, 0.f, 0.f, 0.f};
#pragma unroll
  for (int kc = 0; kc < 8; ++kc) {
    f16x8 a = *(const f16x8*)&xs[w * 16 + l15][kc * 32 + quad * 8];
#pragma unroll
    for (int ct = 0; ct < 16; ++ct) {
      f16x8 b = *(const f16x8*)(Wto + (ct * 16 + l15) * 256 + kc * 32 + quad * 8);
      acc[ct] = MFMAH(a, b, acc[ct]);
    }
  }
#pragma unroll
  for (int ct = 0; ct < 16; ++ct) {
    float bct = bo[ct * 16 + l15];
#pragma unroll
    for (int r = 0; r < 4; ++r)
      out[(size_t)(rb + w * 16 + quad * 4 + r) * 256 + ct * 16 + l15] = acc[ct][r] + bct;
  }
}

// ---------------------------------------------------------------------------
extern "C" void kernel_launch(void* const* d_in, const int* in_sizes, int n_in,
                              void* d_out, int out_size, void* d_ws, size_t ws_size,
                              hipStream_t stream)
{
  const float* inp = (const float*)d_in[0];
  const float* wq  = (const float*)d_in[1];
  const float* bq  = (const float*)d_in[2];
  const float* wk  = (const float*)d_in[3];
  const float* bk  = (const float*)d_in[4];
  const float* wv  = (const float*)d_in[5];
  const float* bv  = (const float*)d_in[6];
  const float* wo  = (const float*)d_in[7];
  const float* bo  = (const float*)d_in[8];
  float* out = (float*)d_out;

  // ws (~60 MB): Qh, Kf, Vf (NE f16 each), Wt (4*65536 f16), Pp (4*NE f16), m/l
  f16* Qh = (f16*)d_ws;
  f16* Kf = Qh + NE;
  f16* Vf = Kf + NE;
  f16* Wt = Vf + NE;
  f16* Pp = Wt + 4 * 65536;
  float* Mp = (float*)(Pp + 4 * NE);
  float* Lp = Mp + 4 * NROWS;

  prep_wt_kernel<<<dim3(256, 4), 256, 0, stream>>>(wq, wk, wv, wo, Wt);

  qkv_mfma_kernel<<<dim3(256, 3), 256, 0, stream>>>(
      inp, Wt, bq, bk, bv, Qh, Kf, Vf);

  attn6_kernel<<<512, 256, 0, stream>>>(Qh, (const char*)Kf, (const char*)Vf,
                                        Pp, Mp, Lp);

  oproj_mfma_kernel<<<256, 256, 0, stream>>>(Pp, Mp, Lp, Wt + 3 * 65536, bo, out);
}